// Round 1
// baseline (4516.171 us; speedup 1.0000x reference)
//
#include <hip/hip_runtime.h>
#include <hip/hip_bf16.h>

#define NS 512   // states
#define MS 256   // symbols
#define TB 256   // sequence length
#define NB 16    // batches per workgroup
#define NWG 16   // workgroups (256 batches / 16)
#define AP 520   // A-buffer pitch (elements); 1040B row stride -> 16B aligned, bank-rotated

typedef __attribute__((ext_vector_type(8))) short short8;
typedef __attribute__((ext_vector_type(4))) float f32x4;

__global__ void k_emission(const float* __restrict__ E, float* __restrict__ logET) {
    int n = blockIdx.x;
    int lane = threadIdx.x;
    const float* row = E + (size_t)n * MS;
    float v[4]; float mx = -1e30f;
#pragma unroll
    for (int j = 0; j < 4; ++j) { v[j] = row[lane + 64 * j]; mx = fmaxf(mx, v[j]); }
#pragma unroll
    for (int off = 1; off < 64; off <<= 1) mx = fmaxf(mx, __shfl_xor(mx, off));
    float s = 0.f;
#pragma unroll
    for (int j = 0; j < 4; ++j) s += __expf(v[j] - mx);
#pragma unroll
    for (int off = 1; off < 64; off <<= 1) s += __shfl_xor(s, off);
    float lse = mx + __logf(s);
#pragma unroll
    for (int j = 0; j < 4; ++j) logET[(size_t)(lane + 64 * j) * NS + n] = v[j] - lse;
}

__global__ void k_transition(const float* __restrict__ U, __hip_bfloat16* __restrict__ Texp) {
    int k = blockIdx.x;
    int lane = threadIdx.x;
    float v[8]; float mx = -1e30f;
#pragma unroll
    for (int j = 0; j < 8; ++j) { v[j] = U[(size_t)(lane + 64 * j) * NS + k]; mx = fmaxf(mx, v[j]); }
#pragma unroll
    for (int off = 1; off < 64; off <<= 1) mx = fmaxf(mx, __shfl_xor(mx, off));
    float s = 0.f;
#pragma unroll
    for (int j = 0; j < 8; ++j) s += __expf(v[j] - mx);
#pragma unroll
    for (int off = 1; off < 64; off <<= 1) s += __shfl_xor(s, off);
    float lse = mx + __logf(s);
#pragma unroll
    for (int j = 0; j < 8; ++j)
        Texp[(size_t)(lane + 64 * j) * NS + k] = __float2bfloat16(__expf(v[j] - lse));
}

__global__ void k_priors(const float* __restrict__ U, float* __restrict__ lp) {
    int lane = threadIdx.x;
    float v[8]; float mx = -1e30f;
#pragma unroll
    for (int j = 0; j < 8; ++j) { v[j] = U[lane + 64 * j]; mx = fmaxf(mx, v[j]); }
#pragma unroll
    for (int off = 1; off < 64; off <<= 1) mx = fmaxf(mx, __shfl_xor(mx, off));
    float s = 0.f;
#pragma unroll
    for (int j = 0; j < 8; ++j) s += __expf(v[j] - mx);
#pragma unroll
    for (int off = 1; off < 64; off <<= 1) s += __shfl_xor(s, off);
    float lse = mx + __logf(s);
#pragma unroll
    for (int j = 0; j < 8; ++j) lp[lane + 64 * j] = v[j] - lse;
}

__launch_bounds__(256)
__global__ void k_forward(const int* __restrict__ batch, const float* __restrict__ logET,
                          const __hip_bfloat16* __restrict__ Texp,
                          const float* __restrict__ logpri, float* __restrict__ out) {
    __shared__ __align__(16) __hip_bfloat16 Abuf[NB * AP];
    __shared__ int syms[NB * TB];
    __shared__ float red_mx[4 * NB];
    __shared__ float red_sm[4 * NB];
    __shared__ float g_mx[NB];

    const int tid = threadIdx.x;
    const int lane = tid & 63;
    const int wv = tid >> 6;
    const int hi = lane >> 4;
    const int lo = lane & 15;
    const int b0 = blockIdx.x * NB;

    for (int idx = tid; idx < NB * TB; idx += 256)
        syms[idx] = batch[b0 * TB + idx];
    __syncthreads();

    float v[4][8];

    for (int t = 0; t < TB; ++t) {
        if (t == 0) {
#pragma unroll
            for (int r = 0; r < 4; ++r) {
                int sym = syms[(hi * 4 + r) * TB];
#pragma unroll
                for (int nt = 0; nt < 8; ++nt) {
                    int i = wv * 128 + nt * 16 + lo;
                    v[r][nt] = logET[(size_t)sym * NS + i] + logpri[i];
                }
            }
        } else {
            float em[4][8];
            int symr[4];
#pragma unroll
            for (int r = 0; r < 4; ++r) symr[r] = syms[(hi * 4 + r) * TB + t];
#pragma unroll
            for (int r = 0; r < 4; ++r)
#pragma unroll
                for (int nt = 0; nt < 8; ++nt)
                    em[r][nt] = logET[(size_t)symr[r] * NS + wv * 128 + nt * 16 + lo];
            float mprev[4];
#pragma unroll
            for (int r = 0; r < 4; ++r) mprev[r] = g_mx[hi * 4 + r];

            f32x4 acc[8] = {};
#pragma unroll 2
            for (int kb = 0; kb < NS; kb += 32) {
                short8 a = *reinterpret_cast<const short8*>(&Abuf[lo * AP + kb + hi * 8]);
#pragma unroll
                for (int nt = 0; nt < 8; ++nt) {
                    short8 bfrg = *reinterpret_cast<const short8*>(
                        Texp + (size_t)(wv * 128 + nt * 16 + lo) * NS + kb + hi * 8);
                    acc[nt] = __builtin_amdgcn_mfma_f32_16x16x32_bf16(a, bfrg, acc[nt], 0, 0, 0);
                }
            }
#pragma unroll
            for (int r = 0; r < 4; ++r)
#pragma unroll
                for (int nt = 0; nt < 8; ++nt)
                    v[r][nt] = __logf(acc[nt][r]) + mprev[r] + em[r][nt];
        }

        float lm[4];
#pragma unroll
        for (int r = 0; r < 4; ++r) {
            lm[r] = v[r][0];
#pragma unroll
            for (int nt = 1; nt < 8; ++nt) lm[r] = fmaxf(lm[r], v[r][nt]);
        }
#pragma unroll
        for (int off = 1; off < 16; off <<= 1) {
#pragma unroll
            for (int r = 0; r < 4; ++r) lm[r] = fmaxf(lm[r], __shfl_xor(lm[r], off));
        }
        if (lo == 0) {
#pragma unroll
            for (int r = 0; r < 4; ++r) red_mx[wv * NB + hi * 4 + r] = lm[r];
        }
        __syncthreads();
        if (tid < NB) {
            float m = fmaxf(fmaxf(red_mx[tid], red_mx[NB + tid]),
                            fmaxf(red_mx[2 * NB + tid], red_mx[3 * NB + tid]));
            g_mx[tid] = m;
        }
        __syncthreads();

        float ls[4] = {0.f, 0.f, 0.f, 0.f};
#pragma unroll
        for (int r = 0; r < 4; ++r) {
            float gm = g_mx[hi * 4 + r];
#pragma unroll
            for (int nt = 0; nt < 8; ++nt) {
                float a = __expf(v[r][nt] - gm);
                ls[r] += a;
                Abuf[(hi * 4 + r) * AP + wv * 128 + nt * 16 + lo] = __float2bfloat16(a);
            }
        }
#pragma unroll
        for (int off = 1; off < 16; off <<= 1) {
#pragma unroll
            for (int r = 0; r < 4; ++r) ls[r] += __shfl_xor(ls[r], off);
        }
        if (lo == 0) {
#pragma unroll
            for (int r = 0; r < 4; ++r) red_sm[wv * NB + hi * 4 + r] = ls[r];
        }
        __syncthreads();
        if (tid < NB) {
            float s = red_sm[tid] + red_sm[NB + tid] + red_sm[2 * NB + tid] + red_sm[3 * NB + tid];
            out[(size_t)(b0 + tid) * TB + t] = g_mx[tid] + __logf(s);
        }
        __syncthreads();
    }
}

extern "C" void kernel_launch(void* const* d_in, const int* in_sizes, int n_in,
                              void* d_out, int out_size, void* d_ws, size_t ws_size,
                              hipStream_t stream) {
    const int* batch = (const int*)d_in[0];
    const float* unE = (const float*)d_in[1];
    const float* unT = (const float*)d_in[2];
    const float* unP = (const float*)d_in[3];
    float* outp = (float*)d_out;

    float* logET = (float*)d_ws;                            // 256*512 f32
    float* logpri = logET + (size_t)MS * NS;                // 512 f32
    __hip_bfloat16* Texp = (__hip_bfloat16*)(logpri + NS);  // 512*512 bf16

    k_emission<<<NS, 64, 0, stream>>>(unE, logET);
    k_transition<<<NS, 64, 0, stream>>>(unT, Texp);
    k_priors<<<1, 64, 0, stream>>>(unP, logpri);
    k_forward<<<NWG, 256, 0, stream>>>(batch, logET, Texp, logpri, outp);
}

// Round 2
// 2630.562 us; speedup vs baseline: 1.7168x; 1.7168x over previous
//
#include <hip/hip_runtime.h>
#include <hip/hip_bf16.h>

#define NS 512     // states
#define MS 256     // symbols
#define TB 256     // sequence length
#define NGRP 16    // batch groups
#define NSL 4      // state slices (peer WGs) per group
#define SLST 128   // states per slice
#define BPG 16     // batches per group

// workspace byte offsets
#define OFF_LOGET  0u
#define OFF_LOGPRI 524288u
#define OFF_TEXP   526336u
#define OFF_AEX    1050624u   // bf16 [16 grp][2 par][16 b][512 k]  = 512KB
#define OFF_STATS  1574912u   // f32  [16 grp][2 par][4 j][16 b]    = 8KB
#define OFF_FLAGS  1591296u   // int  [64 wg][16]                   = 4KB

typedef __attribute__((ext_vector_type(8))) short short8;
typedef __attribute__((ext_vector_type(4))) float f32x4;

__global__ void k_emission(const float* __restrict__ E, float* __restrict__ logET) {
    int n = blockIdx.x;
    int lane = threadIdx.x;
    const float* row = E + (size_t)n * MS;
    float v[4]; float mx = -1e30f;
#pragma unroll
    for (int j = 0; j < 4; ++j) { v[j] = row[lane + 64 * j]; mx = fmaxf(mx, v[j]); }
#pragma unroll
    for (int off = 1; off < 64; off <<= 1) mx = fmaxf(mx, __shfl_xor(mx, off));
    float s = 0.f;
#pragma unroll
    for (int j = 0; j < 4; ++j) s += __expf(v[j] - mx);
#pragma unroll
    for (int off = 1; off < 64; off <<= 1) s += __shfl_xor(s, off);
    float lse = mx + __logf(s);
#pragma unroll
    for (int j = 0; j < 4; ++j) logET[(size_t)(lane + 64 * j) * NS + n] = v[j] - lse;
}

__global__ void k_transition(const float* __restrict__ U, __hip_bfloat16* __restrict__ Texp) {
    int k = blockIdx.x;
    int lane = threadIdx.x;
    float v[8]; float mx = -1e30f;
#pragma unroll
    for (int j = 0; j < 8; ++j) { v[j] = U[(size_t)(lane + 64 * j) * NS + k]; mx = fmaxf(mx, v[j]); }
#pragma unroll
    for (int off = 1; off < 64; off <<= 1) mx = fmaxf(mx, __shfl_xor(mx, off));
    float s = 0.f;
#pragma unroll
    for (int j = 0; j < 8; ++j) s += __expf(v[j] - mx);
#pragma unroll
    for (int off = 1; off < 64; off <<= 1) s += __shfl_xor(s, off);
    float lse = mx + __logf(s);
#pragma unroll
    for (int j = 0; j < 8; ++j)
        Texp[(size_t)(lane + 64 * j) * NS + k] = __float2bfloat16(__expf(v[j] - lse));
}

__global__ void k_priors(const float* __restrict__ U, float* __restrict__ lp) {
    int lane = threadIdx.x;
    float v[8]; float mx = -1e30f;
#pragma unroll
    for (int j = 0; j < 8; ++j) { v[j] = U[lane + 64 * j]; mx = fmaxf(mx, v[j]); }
#pragma unroll
    for (int off = 1; off < 64; off <<= 1) mx = fmaxf(mx, __shfl_xor(mx, off));
    float s = 0.f;
#pragma unroll
    for (int j = 0; j < 8; ++j) s += __expf(v[j] - mx);
#pragma unroll
    for (int off = 1; off < 64; off <<= 1) s += __shfl_xor(s, off);
    float lse = mx + __logf(s);
#pragma unroll
    for (int j = 0; j < 8; ++j) lp[lane + 64 * j] = v[j] - lse;
}

// 64 WGs: group g = blockIdx/4 owns batches [g*16,g*16+16); slice j = blockIdx%4
// owns output states [j*128, j*128+128) with its T-rows LDS-resident (swizzled).
// Per step: one cross-WG sync (publish A-slice + q row-sums, flag, spin, fence).
__launch_bounds__(256, 1)
__global__ void k_forward(const int* __restrict__ batch, const float* __restrict__ logET,
                          const __hip_bfloat16* __restrict__ Texp,
                          const float* __restrict__ logpri,
                          __hip_bfloat16* __restrict__ Aex,
                          float* __restrict__ stats,
                          int* __restrict__ flags,
                          float* __restrict__ out) {
    __shared__ __align__(16) char Tsl[SLST * 1024];   // 128KB, XOR-swizzled rows
    __shared__ int syms[BPG * TB];                    // 16KB
    __shared__ float red[4 * BPG];

    const int tid = threadIdx.x;
    const int lane = tid & 63;
    const int wv = tid >> 6;      // wave 0..3 -> i_local in [wv*32, wv*32+32)
    const int hi = lane >> 4;     // 0..3
    const int lo = lane & 15;
    const int g  = blockIdx.x >> 2;
    const int j  = blockIdx.x & 3;
    const int b0 = g * BPG;
    const int i0 = j * SLST;

    // ---- stage T slice into LDS with XOR swizzle: byte ^= ((row&7)<<4) ----
    for (int c = tid; c < SLST * 64; c += 256) {
        int i = c >> 6, kc = c & 63;
        short8 vld = *reinterpret_cast<const short8*>(Texp + (size_t)(i0 + i) * NS + kc * 8);
        int off = ((i << 10) + (kc << 4)) ^ ((i & 7) << 4);
        *reinterpret_cast<short8*>(Tsl + off) = vld;
    }
    for (int idx = tid; idx < BPG * TB; idx += 256)
        syms[idx] = batch[b0 * TB + idx];
    __syncthreads();

    const int myflag = blockIdx.x * 16;
    const int p0 = (g * 4 + ((j + 1) & 3)) * 16;
    const int p1 = (g * 4 + ((j + 2) & 3)) * 16;
    const int p2 = (g * 4 + ((j + 3) & 3)) * 16;

    float nrm[4];

    // ---- prologue t = 0: alpha0 = em + priors, nrm = 0 ----
    {
        float ls[4] = {0.f, 0.f, 0.f, 0.f};
#pragma unroll
        for (int r = 0; r < 4; ++r) {
            nrm[r] = 0.f;
            int sym = syms[(hi * 4 + r) * TB];
#pragma unroll
            for (int nt = 0; nt < 2; ++nt) {
                int i = i0 + wv * 32 + nt * 16 + lo;
                float v = logET[(size_t)sym * NS + i] + logpri[i];
                float a = __expf(v);
                ls[r] += a;
                Aex[((size_t)(g * 2 + 0) * BPG + (hi * 4 + r)) * NS + i] = __float2bfloat16(a);
            }
        }
#pragma unroll
        for (int off = 1; off < 16; off <<= 1)
#pragma unroll
            for (int r = 0; r < 4; ++r) ls[r] += __shfl_xor(ls[r], off);
        if (lo == 0)
#pragma unroll
            for (int r = 0; r < 4; ++r) red[wv * BPG + hi * 4 + r] = ls[r];
        __syncthreads();
        if (tid < BPG) {
            float q = red[tid] + red[BPG + tid] + red[2 * BPG + tid] + red[3 * BPG + tid];
            stats[((g * 2 + 0) * NSL + j) * BPG + tid] = q;
        }
        if (tid == 0) {
            __threadfence();
            __hip_atomic_store(&flags[myflag], 1, __ATOMIC_RELAXED, __HIP_MEMORY_SCOPE_AGENT);
        }
        __syncthreads();
    }

    // ---- main scan ----
    for (int t = 1; t < TB; ++t) {
        const int parR = (t - 1) & 1, parW = t & 1;

        // prefetch emissions (constant data -> safe before fence)
        float em[4][2];
#pragma unroll
        for (int r = 0; r < 4; ++r) {
            int sym = syms[(hi * 4 + r) * TB + t];
#pragma unroll
            for (int nt = 0; nt < 2; ++nt)
                em[r][nt] = logET[(size_t)sym * NS + i0 + wv * 32 + nt * 16 + lo];
        }

        // wait for all peers to have published step t-1
        while (__hip_atomic_load(&flags[p0], __ATOMIC_RELAXED, __HIP_MEMORY_SCOPE_AGENT) < t ||
               __hip_atomic_load(&flags[p1], __ATOMIC_RELAXED, __HIP_MEMORY_SCOPE_AGENT) < t ||
               __hip_atomic_load(&flags[p2], __ATOMIC_RELAXED, __HIP_MEMORY_SCOPE_AGENT) < t) {
            __builtin_amdgcn_s_sleep(1);
        }
        __threadfence();   // acquire: invalidate L1/L2 so A/stats reads are fresh

        // read q(t-1): out(t-1), new normalizer
        float qv[4][4];
#pragma unroll
        for (int jj = 0; jj < 4; ++jj)
#pragma unroll
            for (int r = 0; r < 4; ++r)
                qv[jj][r] = stats[((g * 2 + parR) * NSL + jj) * BPG + hi * 4 + r];
        float nrmN[4];
#pragma unroll
        for (int r = 0; r < 4; ++r) {
            float qs = qv[0][r] + qv[1][r] + qv[2][r] + qv[3][r];
            float qm = fmaxf(fmaxf(qv[0][r], qv[1][r]), fmaxf(qv[2][r], qv[3][r]));
            if (j == 0 && wv == 0 && lo == 0)
                out[(size_t)(b0 + hi * 4 + r) * TB + (t - 1)] = nrm[r] + __logf(qs);
            nrmN[r] = nrm[r] + __logf(qm);
        }

        // GEMM: P[b, i_slice] = sum_k A(t-1)[b,k] * T[i,k], K = 512
        f32x4 acc[2] = {};
        const __hip_bfloat16* Ab = Aex + (size_t)(g * 2 + parR) * BPG * NS;
#pragma unroll 4
        for (int kb = 0; kb < NS; kb += 32) {
            short8 a = *reinterpret_cast<const short8*>(Ab + (size_t)lo * NS + kb + hi * 8);
#pragma unroll
            for (int nt = 0; nt < 2; ++nt) {
                int il = wv * 32 + nt * 16 + lo;
                int off = ((il << 10) + ((kb + hi * 8) << 1)) ^ ((il & 7) << 4);
                short8 bfr = *reinterpret_cast<const short8*>(Tsl + off);
                acc[nt] = __builtin_amdgcn_mfma_f32_16x16x32_bf16(a, bfr, acc[nt], 0, 0, 0);
            }
        }

        // epilogue: v = log(P) + nrm + em; publish A(t) = exp(v - nrmN), q = row sums
        float ls[4] = {0.f, 0.f, 0.f, 0.f};
#pragma unroll
        for (int r = 0; r < 4; ++r) {
#pragma unroll
            for (int nt = 0; nt < 2; ++nt) {
                float v = __logf(acc[nt][r]) + nrm[r] + em[r][nt];
                float a = __expf(v - nrmN[r]);
                ls[r] += a;
                Aex[((size_t)(g * 2 + parW) * BPG + (hi * 4 + r)) * NS +
                    i0 + wv * 32 + nt * 16 + lo] = __float2bfloat16(a);
            }
            nrm[r] = nrmN[r];
        }
#pragma unroll
        for (int off = 1; off < 16; off <<= 1)
#pragma unroll
            for (int r = 0; r < 4; ++r) ls[r] += __shfl_xor(ls[r], off);
        if (lo == 0)
#pragma unroll
            for (int r = 0; r < 4; ++r) red[wv * BPG + hi * 4 + r] = ls[r];
        __syncthreads();   // drains all waves' global A-stores too
        if (tid < BPG) {
            float q = red[tid] + red[BPG + tid] + red[2 * BPG + tid] + red[3 * BPG + tid];
            stats[((g * 2 + parW) * NSL + j) * BPG + tid] = q;
        }
        if (tid == 0) {
            __threadfence();   // release: writeback L2 before flag
            __hip_atomic_store(&flags[myflag], t + 1, __ATOMIC_RELAXED, __HIP_MEMORY_SCOPE_AGENT);
        }
        __syncthreads();   // keep fast waves from racing into red[] next step
    }

    // ---- final output column t = 255 ----
    if (j == 0) {
        while (__hip_atomic_load(&flags[p0], __ATOMIC_RELAXED, __HIP_MEMORY_SCOPE_AGENT) < 256 ||
               __hip_atomic_load(&flags[p1], __ATOMIC_RELAXED, __HIP_MEMORY_SCOPE_AGENT) < 256 ||
               __hip_atomic_load(&flags[p2], __ATOMIC_RELAXED, __HIP_MEMORY_SCOPE_AGENT) < 256) {
            __builtin_amdgcn_s_sleep(1);
        }
        __threadfence();
        if (wv == 0 && lo == 0) {
#pragma unroll
            for (int r = 0; r < 4; ++r) {
                float qs = 0.f;
#pragma unroll
                for (int jj = 0; jj < 4; ++jj)
                    qs += stats[((g * 2 + 1) * NSL + jj) * BPG + hi * 4 + r];
                out[(size_t)(b0 + hi * 4 + r) * TB + 255] = nrm[r] + __logf(qs);
            }
        }
    }
}

extern "C" void kernel_launch(void* const* d_in, const int* in_sizes, int n_in,
                              void* d_out, int out_size, void* d_ws, size_t ws_size,
                              hipStream_t stream) {
    const int* batch = (const int*)d_in[0];
    const float* unE = (const float*)d_in[1];
    const float* unT = (const float*)d_in[2];
    const float* unP = (const float*)d_in[3];
    float* outp = (float*)d_out;

    char* ws = (char*)d_ws;
    float* logET = (float*)(ws + OFF_LOGET);
    float* logpri = (float*)(ws + OFF_LOGPRI);
    __hip_bfloat16* Texp = (__hip_bfloat16*)(ws + OFF_TEXP);
    __hip_bfloat16* Aex = (__hip_bfloat16*)(ws + OFF_AEX);
    float* stats = (float*)(ws + OFF_STATS);
    int* flags = (int*)(ws + OFF_FLAGS);

    hipMemsetAsync(flags, 0, 64 * 16 * sizeof(int), stream);
    k_emission<<<NS, 64, 0, stream>>>(unE, logET);
    k_transition<<<NS, 64, 0, stream>>>(unT, Texp);
    k_priors<<<1, 64, 0, stream>>>(unP, logpri);
    k_forward<<<NGRP * NSL, 256, 0, stream>>>(batch, logET, Texp, logpri,
                                              Aex, stats, flags, outp);
}

// Round 3
// 1585.575 us; speedup vs baseline: 2.8483x; 1.6591x over previous
//
#include <hip/hip_runtime.h>
#include <hip/hip_bf16.h>

#define NS 512     // states
#define MS 256     // symbols
#define TB 256     // sequence length
#define NGRP 16    // batch groups
#define NSL 4      // state slices (peer WGs) per group
#define SLST 128   // states per slice
#define BPG 16     // batches per group

// workspace byte offsets
#define OFF_LOGET  0u
#define OFF_LOGPRI 524288u
#define OFF_TEXP   526336u
#define OFF_AEX    1050624u   // bf16 [16 grp][2 par][16 b][512 k]  = 512KB
#define OFF_STATS  1574912u   // f32  [16 grp][2 par][4 j][16 b]    = 8KB
#define OFF_FLAGS  1591296u   // int  [64 wg][16]                   = 4KB

typedef __attribute__((ext_vector_type(8))) short short8;
typedef __attribute__((ext_vector_type(4))) float f32x4;

__device__ __forceinline__ unsigned long long ld_u64_agent(const void* p) {
    return __hip_atomic_load((const unsigned long long*)p, __ATOMIC_RELAXED,
                             __HIP_MEMORY_SCOPE_AGENT);
}
__device__ __forceinline__ unsigned ld_u32_agent(const void* p) {
    return __hip_atomic_load((const unsigned*)p, __ATOMIC_RELAXED,
                             __HIP_MEMORY_SCOPE_AGENT);
}
__device__ __forceinline__ void st_u16_agent(void* p, unsigned short v) {
    __hip_atomic_store((unsigned short*)p, v, __ATOMIC_RELAXED,
                       __HIP_MEMORY_SCOPE_AGENT);
}
__device__ __forceinline__ void st_u32_agent(void* p, unsigned v) {
    __hip_atomic_store((unsigned*)p, v, __ATOMIC_RELAXED,
                       __HIP_MEMORY_SCOPE_AGENT);
}
__device__ __forceinline__ float u2f(unsigned u) { float f; __builtin_memcpy(&f, &u, 4); return f; }
__device__ __forceinline__ unsigned f2u(float f) { unsigned u; __builtin_memcpy(&u, &f, 4); return u; }
__device__ __forceinline__ unsigned short f2bf_bits(float f) {
    __hip_bfloat16 h = __float2bfloat16(f);
    unsigned short u; __builtin_memcpy(&u, &h, 2); return u;
}

__global__ void k_emission(const float* __restrict__ E, float* __restrict__ logET) {
    int n = blockIdx.x;
    int lane = threadIdx.x;
    const float* row = E + (size_t)n * MS;
    float v[4]; float mx = -1e30f;
#pragma unroll
    for (int j = 0; j < 4; ++j) { v[j] = row[lane + 64 * j]; mx = fmaxf(mx, v[j]); }
#pragma unroll
    for (int off = 1; off < 64; off <<= 1) mx = fmaxf(mx, __shfl_xor(mx, off));
    float s = 0.f;
#pragma unroll
    for (int j = 0; j < 4; ++j) s += __expf(v[j] - mx);
#pragma unroll
    for (int off = 1; off < 64; off <<= 1) s += __shfl_xor(s, off);
    float lse = mx + __logf(s);
#pragma unroll
    for (int j = 0; j < 4; ++j) logET[(size_t)(lane + 64 * j) * NS + n] = v[j] - lse;
}

__global__ void k_transition(const float* __restrict__ U, __hip_bfloat16* __restrict__ Texp) {
    int k = blockIdx.x;
    int lane = threadIdx.x;
    float v[8]; float mx = -1e30f;
#pragma unroll
    for (int j = 0; j < 8; ++j) { v[j] = U[(size_t)(lane + 64 * j) * NS + k]; mx = fmaxf(mx, v[j]); }
#pragma unroll
    for (int off = 1; off < 64; off <<= 1) mx = fmaxf(mx, __shfl_xor(mx, off));
    float s = 0.f;
#pragma unroll
    for (int j = 0; j < 8; ++j) s += __expf(v[j] - mx);
#pragma unroll
    for (int off = 1; off < 64; off <<= 1) s += __shfl_xor(s, off);
    float lse = mx + __logf(s);
#pragma unroll
    for (int j = 0; j < 8; ++j)
        Texp[(size_t)(lane + 64 * j) * NS + k] = __float2bfloat16(__expf(v[j] - lse));
}

__global__ void k_priors(const float* __restrict__ U, float* __restrict__ lp) {
    int lane = threadIdx.x;
    float v[8]; float mx = -1e30f;
#pragma unroll
    for (int j = 0; j < 8; ++j) { v[j] = U[lane + 64 * j]; mx = fmaxf(mx, v[j]); }
#pragma unroll
    for (int off = 1; off < 64; off <<= 1) mx = fmaxf(mx, __shfl_xor(mx, off));
    float s = 0.f;
#pragma unroll
    for (int j = 0; j < 8; ++j) s += __expf(v[j] - mx);
#pragma unroll
    for (int off = 1; off < 64; off <<= 1) s += __shfl_xor(s, off);
    float lse = mx + __logf(s);
#pragma unroll
    for (int j = 0; j < 8; ++j) lp[lane + 64 * j] = v[j] - lse;
}

// 64 WGs: group g = blockIdx/4 owns batches [g*16,g*16+16); slice j = blockIdx%4
// owns output states [j*128,(j+1)*128) with its T-rows LDS-resident (swizzled).
// Cross-WG exchange entirely via agent-scope (sc1) relaxed atomics -> MALL/L3;
// no threadfence (no L2 invalidation). Flag ordering via __syncthreads vmcnt drain.
__launch_bounds__(256, 1)
__global__ void k_forward(const int* __restrict__ batch, const float* __restrict__ logET,
                          const __hip_bfloat16* __restrict__ Texp,
                          const float* __restrict__ logpri,
                          __hip_bfloat16* __restrict__ Aex,
                          unsigned* __restrict__ stats,
                          int* __restrict__ flags,
                          float* __restrict__ out) {
    __shared__ __align__(16) char Tsl[SLST * 1024];   // 128KB, XOR-swizzled rows
    __shared__ int syms[BPG * TB];                    // 16KB
    __shared__ float red[4 * BPG];

    const int tid = threadIdx.x;
    const int lane = tid & 63;
    const int wv = tid >> 6;
    const int hi = lane >> 4;
    const int lo = lane & 15;
    const int g  = blockIdx.x >> 2;
    const int j  = blockIdx.x & 3;
    const int b0 = g * BPG;
    const int i0 = j * SLST;

    // ---- stage T slice into LDS with XOR swizzle: byte ^= ((row&7)<<4) ----
    for (int c = tid; c < SLST * 64; c += 256) {
        int i = c >> 6, kc = c & 63;
        short8 vld = *reinterpret_cast<const short8*>(Texp + (size_t)(i0 + i) * NS + kc * 8);
        int off = ((i << 10) + (kc << 4)) ^ ((i & 7) << 4);
        *reinterpret_cast<short8*>(Tsl + off) = vld;
    }
    for (int idx = tid; idx < BPG * TB; idx += 256)
        syms[idx] = batch[b0 * TB + idx];
    __syncthreads();

    const int myflag = blockIdx.x * 16;
    int pidx = 0;
    if (tid < 3) pidx = (g * 4 + ((j + 1 + tid) & 3)) * 16;

    float nrm[4];

    // ---- prologue t = 0 ----
    {
        float ls[4] = {0.f, 0.f, 0.f, 0.f};
#pragma unroll
        for (int r = 0; r < 4; ++r) {
            nrm[r] = 0.f;
            int sym = syms[(hi * 4 + r) * TB];
#pragma unroll
            for (int nt = 0; nt < 2; ++nt) {
                int i = i0 + wv * 32 + nt * 16 + lo;
                float v = logET[(size_t)sym * NS + i] + logpri[i];
                float a = __expf(v);
                ls[r] += a;
                st_u16_agent(&Aex[((size_t)(g * 2 + 0) * BPG + (hi * 4 + r)) * NS + i],
                             f2bf_bits(a));
            }
        }
#pragma unroll
        for (int off = 1; off < 16; off <<= 1)
#pragma unroll
            for (int r = 0; r < 4; ++r) ls[r] += __shfl_xor(ls[r], off);
        if (lo == 0)
#pragma unroll
            for (int r = 0; r < 4; ++r) red[wv * BPG + hi * 4 + r] = ls[r];
        __syncthreads();                 // drains A stores (vmcnt) + red visible
        if (tid < BPG) {
            float q = red[tid] + red[BPG + tid] + red[2 * BPG + tid] + red[3 * BPG + tid];
            st_u32_agent(&stats[((g * 2 + 0) * NSL + j) * BPG + tid], f2u(q));
        }
        __syncthreads();                 // drains stats stores
        if (tid == 0)
            __hip_atomic_store(&flags[myflag], 1, __ATOMIC_RELAXED, __HIP_MEMORY_SCOPE_AGENT);
    }

    union U16B { unsigned long long q[2]; short8 s; };

    // ---- main scan ----
    for (int t = 1; t < TB; ++t) {
        const int parR = (t - 1) & 1, parW = t & 1;

        // emission prefetch (constant data, L2-warm)
        float em[4][2];
#pragma unroll
        for (int r = 0; r < 4; ++r) {
            int sym = syms[(hi * 4 + r) * TB + t];
#pragma unroll
            for (int nt = 0; nt < 2; ++nt)
                em[r][nt] = logET[(size_t)sym * NS + i0 + wv * 32 + nt * 16 + lo];
        }

        // 3 lanes poll the 3 peer flags (one address each, same loop)
        if (tid < 3) {
            while (__hip_atomic_load(&flags[pidx], __ATOMIC_RELAXED,
                                     __HIP_MEMORY_SCOPE_AGENT) < t) { }
        }
        __syncthreads();   // exec + memory barrier: everyone sees spin done

        // A fragments: row lo of A(t-1), 16B per k-block, via sc1 u64 loads
        U16B af[16];
        const char* Ab = (const char*)(Aex + ((size_t)(g * 2 + parR) * BPG + lo) * NS);
#pragma unroll
        for (int kb16 = 0; kb16 < 16; ++kb16) {
            int boff = kb16 * 64 + hi * 16;
            af[kb16].q[0] = ld_u64_agent(Ab + boff);
            af[kb16].q[1] = ld_u64_agent(Ab + boff + 8);
        }
        // stats(t-1): q row-sums of all 4 slices
        float qv[4][4];
#pragma unroll
        for (int jj = 0; jj < 4; ++jj)
#pragma unroll
            for (int r = 0; r < 4; ++r)
                qv[jj][r] = u2f(ld_u32_agent(
                    &stats[((g * 2 + parR) * NSL + jj) * BPG + hi * 4 + r]));

        // GEMM: P[b, i_slice] = sum_k A(t-1)[b,k] * T[i,k]
        f32x4 acc[2] = {};
#pragma unroll
        for (int kb16 = 0; kb16 < 16; ++kb16) {
#pragma unroll
            for (int nt = 0; nt < 2; ++nt) {
                int il = wv * 32 + nt * 16 + lo;
                int off = ((il << 10) + ((kb16 * 32 + hi * 8) << 1)) ^ ((il & 7) << 4);
                short8 bfr = *reinterpret_cast<const short8*>(Tsl + off);
                acc[nt] = __builtin_amdgcn_mfma_f32_16x16x32_bf16(af[kb16].s, bfr, acc[nt], 0, 0, 0);
            }
        }

        // out(t-1), new normalizer
        float nrmN[4];
#pragma unroll
        for (int r = 0; r < 4; ++r) {
            float qs = qv[0][r] + qv[1][r] + qv[2][r] + qv[3][r];
            float qm = fmaxf(fmaxf(qv[0][r], qv[1][r]), fmaxf(qv[2][r], qv[3][r]));
            if (j == 0 && wv == 0 && lo == 0)
                out[(size_t)(b0 + hi * 4 + r) * TB + (t - 1)] = nrm[r] + __logf(qs);
            nrmN[r] = nrm[r] + __logf(qm);
        }

        // epilogue: v = log(P)+nrm+em; publish A(t)=exp(v-nrmN) (sc1 u16), q sums
        float ls[4] = {0.f, 0.f, 0.f, 0.f};
#pragma unroll
        for (int r = 0; r < 4; ++r) {
#pragma unroll
            for (int nt = 0; nt < 2; ++nt) {
                float v = __logf(acc[nt][r]) + nrm[r] + em[r][nt];
                float a = __expf(v - nrmN[r]);
                ls[r] += a;
                st_u16_agent(&Aex[((size_t)(g * 2 + parW) * BPG + (hi * 4 + r)) * NS +
                                  i0 + wv * 32 + nt * 16 + lo],
                             f2bf_bits(a));
            }
            nrm[r] = nrmN[r];
        }
#pragma unroll
        for (int off = 1; off < 16; off <<= 1)
#pragma unroll
            for (int r = 0; r < 4; ++r) ls[r] += __shfl_xor(ls[r], off);
        if (lo == 0)
#pragma unroll
            for (int r = 0; r < 4; ++r) red[wv * BPG + hi * 4 + r] = ls[r];
        __syncthreads();                 // drains all A stores + red visible
        if (tid < BPG) {
            float q = red[tid] + red[BPG + tid] + red[2 * BPG + tid] + red[3 * BPG + tid];
            st_u32_agent(&stats[((g * 2 + parW) * NSL + j) * BPG + tid], f2u(q));
        }
        __syncthreads();                 // drains stats stores
        if (tid == 0)
            __hip_atomic_store(&flags[myflag], t + 1, __ATOMIC_RELAXED, __HIP_MEMORY_SCOPE_AGENT);
    }

    // ---- final output column t = 255 ----
    if (j == 0) {
        if (tid < 3) {
            while (__hip_atomic_load(&flags[pidx], __ATOMIC_RELAXED,
                                     __HIP_MEMORY_SCOPE_AGENT) < TB) { }
        }
        __syncthreads();
        if (wv == 0 && lo == 0) {
#pragma unroll
            for (int r = 0; r < 4; ++r) {
                float qs = 0.f;
#pragma unroll
                for (int jj = 0; jj < 4; ++jj)
                    qs += u2f(ld_u32_agent(
                        &stats[((g * 2 + 1) * NSL + jj) * BPG + hi * 4 + r]));
                out[(size_t)(b0 + hi * 4 + r) * TB + 255] = nrm[r] + __logf(qs);
            }
        }
    }
}

extern "C" void kernel_launch(void* const* d_in, const int* in_sizes, int n_in,
                              void* d_out, int out_size, void* d_ws, size_t ws_size,
                              hipStream_t stream) {
    const int* batch = (const int*)d_in[0];
    const float* unE = (const float*)d_in[1];
    const float* unT = (const float*)d_in[2];
    const float* unP = (const float*)d_in[3];
    float* outp = (float*)d_out;

    char* ws = (char*)d_ws;
    float* logET = (float*)(ws + OFF_LOGET);
    float* logpri = (float*)(ws + OFF_LOGPRI);
    __hip_bfloat16* Texp = (__hip_bfloat16*)(ws + OFF_TEXP);
    __hip_bfloat16* Aex = (__hip_bfloat16*)(ws + OFF_AEX);
    unsigned* stats = (unsigned*)(ws + OFF_STATS);
    int* flags = (int*)(ws + OFF_FLAGS);

    hipMemsetAsync(flags, 0, 64 * 16 * sizeof(int), stream);
    k_emission<<<NS, 64, 0, stream>>>(unE, logET);
    k_transition<<<NS, 64, 0, stream>>>(unT, Texp);
    k_priors<<<1, 64, 0, stream>>>(unP, logpri);
    k_forward<<<NGRP * NSL, 256, 0, stream>>>(batch, logET, Texp, logpri,
                                              Aex, stats, flags, outp);
}